// Round 9
// baseline (323.616 us; speedup 1.0000x reference)
//
#include <hip/hip_runtime.h>
#include <hip/hip_bf16.h>

typedef unsigned short u16;
typedef __bf16 bf16x8 __attribute__((ext_vector_type(8)));
typedef float f32x4 __attribute__((ext_vector_type(4)));

#define NROWS 32768
#define H 512
#define NS 8
#define NR 64
#define NT 12

// workspace layout (bytes)
#define WS_W1T   0            // [8][512 n][512 k] bf16 = 4194304
#define WS_UCT   4194304      // [512 r][512 k] bf16    = 524288
#define WS_W2T   4718592      // [8][16 t][512 k] bf16  = 131072
#define WS_CVEC  4849664      // [8][64] f32            = 2048
#define WS_ALPH  4851712      // [8][32768] f32         = 1048576

union BFU { __bf16 h; u16 u; };
__device__ __forceinline__ u16 f2bf(float v) { BFU b; b.h = (__bf16)v; return b.u; }

__device__ __forceinline__ void gload16(const u16* g, u16* l) {
  __builtin_amdgcn_global_load_lds(
      (const __attribute__((address_space(1))) unsigned int*)g,
      (__attribute__((address_space(3))) unsigned int*)l, 16, 0, 0);
}

// ---------- fused prep: 3 transposes + compute_c in one launch ----------
__global__ __launch_bounds__(256) void prep(
    const float* __restrict__ W1, u16* __restrict__ W1T,
    const float* __restrict__ Us, u16* __restrict__ UcatT,
    const float* __restrict__ W2, u16* __restrict__ W2T,
    const float* __restrict__ mu, float* __restrict__ cvec) {
  __shared__ float tile[32][33];
  const int bid = blockIdx.x;
  const int tx = threadIdx.x, ty = threadIdx.y;
  if (bid < 2432) {
    const float* in; u16* out; int Rr, Cc, Cpad, b, r0, c0;
    if (bid < 2048) {
      in = W1; out = W1T; Rr = 512; Cc = 512; Cpad = 512;
      r0 = (bid & 15) * 32; c0 = ((bid >> 4) & 15) * 32; b = bid >> 8;
    } else if (bid < 2304) {
      int t2 = bid - 2048; in = Us; out = UcatT; Rr = 512; Cc = 64; Cpad = 64;
      r0 = (t2 & 15) * 32; c0 = ((t2 >> 4) & 1) * 32; b = t2 >> 5;
    } else {
      int t2 = bid - 2304; in = W2; out = W2T; Rr = 512; Cc = 12; Cpad = 16;
      r0 = (t2 & 15) * 32; c0 = 0; b = t2 >> 4;
    }
#pragma unroll
    for (int i = 0; i < 4; i++) {
      int r = r0 + ty + i * 8, c = c0 + tx;
      float v = 0.f;
      if (r < Rr && c < Cc) v = in[((size_t)b * Rr + r) * Cc + c];
      tile[ty + i * 8][tx] = v;
    }
    __syncthreads();
#pragma unroll
    for (int i = 0; i < 4; i++) {
      int c = c0 + ty + i * 8, r = r0 + tx;
      if (c < Cpad && r < Rr) out[((size_t)b * Cpad + c) * Rr + r] = f2bf(tile[tx][ty + i * 8]);
    }
  } else {
    const int tid = ty * 32 + tx;
    const int idx = (bid - 2432) * 4 + (tid >> 6);   // (s,r) pair, 0..511
    const int s = idx >> 6, r = idx & 63, t = tid & 63;
    float acc = 0.f;
#pragma unroll
    for (int k = t; k < H; k += 64) acc += mu[s * H + k] * Us[((size_t)s * H + k) * NR + r];
#pragma unroll
    for (int m = 32; m; m >>= 1) acc += __shfl_xor(acc, m, 64);
    if (t == 0) cvec[idx] = acc;
  }
}

// ---------- routing (round-0 known-good): alphaT[s][n] ----------
__device__ __forceinline__ void stage32r(const u16* __restrict__ g, u16* l, int wave, int lane) {
#pragma unroll
  for (int i = 0; i < 8; i++) {
    int r = wave * 8 + i;
    gload16(g + (size_t)r * 512 + (size_t)((lane ^ (r & 7)) * 8), l + r * 512);
  }
}

__global__ __launch_bounds__(256, 2) void routing(
    const float* __restrict__ enc, const u16* __restrict__ UcatT,
    const float* __restrict__ cvec, float* __restrict__ alphT) {
  __shared__ __align__(16) u16 Wst[2][32 * 512];
  __shared__ float distS[NS][64];

  const int tid = threadIdx.x;
  const int wave = tid >> 6, lane = tid & 63;
  const int lnm = lane & 15, lnq = lane >> 4;
  const int row0 = blockIdx.x * 64;

  bf16x8 afrag[16];
  {
    const float* rp = enc + (size_t)(row0 + wave * 16 + lnm) * H + lnq * 8;
#pragma unroll
    for (int ks = 0; ks < 16; ks++) {
      float4 x0 = *(const float4*)(rp + ks * 32);
      float4 x1 = *(const float4*)(rp + ks * 32 + 4);
      bf16x8 a;
      a[0] = (__bf16)x0.x; a[1] = (__bf16)x0.y; a[2] = (__bf16)x0.z; a[3] = (__bf16)x0.w;
      a[4] = (__bf16)x1.x; a[5] = (__bf16)x1.y; a[6] = (__bf16)x1.z; a[7] = (__bf16)x1.w;
      afrag[ks] = a;
    }
  }

  stage32r(UcatT, Wst[0], wave, lane);
  float dsq[4] = {0.f, 0.f, 0.f, 0.f};
#pragma unroll 1
  for (int q = 0; q < 16; q++) {
    int s = q >> 1, half = q & 1;
    __syncthreads();
    if (q < 15) stage32r(UcatT + (size_t)(q + 1) * 32 * 512, Wst[(q + 1) & 1], wave, lane);
    const u16* buf = Wst[q & 1];
    f32x4 acc[2] = {};
#pragma unroll
    for (int ks = 0; ks < 16; ks++) {
      int uu = ((ks * 4 + lnq) ^ (lnm & 7)) * 8;
      bf16x8 b0 = *(const bf16x8*)&buf[lnm * 512 + uu];
      bf16x8 b1v = *(const bf16x8*)&buf[(16 + lnm) * 512 + uu];
      acc[0] = __builtin_amdgcn_mfma_f32_16x16x32_bf16(afrag[ks], b0, acc[0], 0, 0, 0);
      acc[1] = __builtin_amdgcn_mfma_f32_16x16x32_bf16(afrag[ks], b1v, acc[1], 0, 0, 0);
    }
#pragma unroll
    for (int ct = 0; ct < 2; ct++) {
      float cv = cvec[s * 64 + half * 32 + ct * 16 + lnm];
#pragma unroll
      for (int g = 0; g < 4; g++) { float d = acc[ct][g] - cv; dsq[g] += d * d; }
    }
    if (half == 1) {
#pragma unroll
      for (int m = 1; m < 16; m <<= 1) {
#pragma unroll
        for (int g = 0; g < 4; g++) dsq[g] += __shfl_xor(dsq[g], m, 16);
      }
      if (lnm == 0) {
#pragma unroll
        for (int g = 0; g < 4; g++) distS[s][wave * 16 + lnq * 4 + g] = sqrtf(dsq[g]);
      }
#pragma unroll
      for (int g = 0; g < 4; g++) dsq[g] = 0.f;
    }
  }
  __syncthreads();
  if (tid < 64) {
    float dmin = distS[0][tid];
#pragma unroll
    for (int s = 1; s < NS; s++) dmin = fminf(dmin, distS[s][tid]);
    float den = 0.f, e[NS];
#pragma unroll
    for (int s = 0; s < NS; s++) { e[s] = __expf(dmin - distS[s][tid]); den += e[s]; }
    float inv = 1.f / den;
#pragma unroll
    for (int s = 0; s < NS; s++) alphT[(size_t)s * NROWS + row0 + tid] = e[s] * inv;
  }
}

// ---------- main classifier (round-6 pipeline, 4-blocks/CU geometry) ----------
// Grid: 1024 = 256 row-blocks (128 rows) x 4 source-groups (2 sources).
// 8 KB chunks (32 wcols x 128 K-quarter), triple-buffered: LDS total 35840 B
// -> 4 blocks/CU (16 waves/CU) if VGPR stays <=128.  Same phase count (128)
// and identical per-CU LDS-read/MFMA totals as the 157us config — only the
// number of INDEPENDENT blocks per CU doubles, to fill the LDS pipe (73%
// busy, 27% idle from aligned burst phases of just 2 blocks).
// Proven protocol per phase: issue stage(q+1) -> own-stage-retire vmcnt ->
// s_barrier -> MFMA from Wst[q%3].  FIFO (2-load stages, 3 epi loads/wc):
//   kq0: [stage(q)2][epi3][stage(q+1)2] -> vmcnt(5)
//   kq1: [epi3][stage(q+1)2][stage(q+2)2] -> vmcnt(2) (epi retired: 1 phase old)
//   kq2/kq3: [stage 2][stage 2] -> vmcnt(2);  last phase: vmcnt(0)
#define H1STR 40   // u16 row stride (80 B)

__device__ __forceinline__ void stageW8(const u16* __restrict__ g, u16* l, int tid) {
  // 32 rows x 128 u16 (256 B/row = 16x16B units); global row stride 512 u16;
  // XOR-swizzle low 3 bits of unit index (bijective; bit3 preserved)
#pragma unroll
  for (int i = 0; i < 2; i++) {
    int flat = tid + i * 256;          // 0..511
    int r = flat >> 4, u = flat & 15;  // r 0..31, u 0..15
    gload16(g + (size_t)r * 512 + ((u ^ (r & 7)) * 8), l + flat * 8);
  }
}

// chunk q in [0,128): j=q>>6 (source in group), wc=(q>>2)&15, kq=q&3
__device__ __forceinline__ const u16* chunk_base(const u16* W1g, int q) {
  return W1g + ((size_t)((q >> 6) * 512 + ((q >> 2) & 15) * 32)) * 512 + (q & 3) * 128;
}

#define KQ_PHASE(KQ, VM)                                                        \
  {                                                                             \
    const int q = j * 64 + wc * 4 + KQ;                                         \
    const int nb = (cb == 2) ? 0 : cb + 1;                                      \
    if (q + 1 < 128) {                                                          \
      stageW8(chunk_base(W1g, q + 1), Wst[nb], tid);                            \
      asm volatile("s_waitcnt vmcnt(" VM ")" ::: "memory");                     \
    } else {                                                                    \
      asm volatile("s_waitcnt vmcnt(0)" ::: "memory");                          \
    }                                                                           \
    __builtin_amdgcn_s_barrier();                                               \
    const u16* buf = Wst[cb];                                                   \
    __builtin_amdgcn_s_setprio(1);                                              \
    _Pragma("unroll")                                                           \
    for (int ksl = 0; ksl < 4; ksl++) {                                         \
      const int uu = ((ksl * 4 + lnq) ^ (lnm & 7)) * 8;                         \
      bf16x8 w0 = *(const bf16x8*)&buf[lnm * 128 + uu];                         \
      bf16x8 w1 = *(const bf16x8*)&buf[(16 + lnm) * 128 + uu];                  \
      _Pragma("unroll")                                                         \
      for (int t = 0; t < 2; t++) {                                             \
        acc[t][0] = __builtin_amdgcn_mfma_f32_16x16x32_bf16(                    \
            w0, efrag[t][KQ * 4 + ksl], acc[t][0], 0, 0, 0);                    \
        acc[t][1] = __builtin_amdgcn_mfma_f32_16x16x32_bf16(                    \
            w1, efrag[t][KQ * 4 + ksl], acc[t][1], 0, 0, 0);                    \
      }                                                                         \
    }                                                                           \
    __builtin_amdgcn_s_setprio(0);                                              \
    cb = nb;                                                                    \
  }

__global__ __launch_bounds__(256, 2) void moe_main(
    const float* __restrict__ enc, const u16* __restrict__ W1T,
    const u16* __restrict__ W2T, const float* __restrict__ alphT,
    const float* __restrict__ b1g, const float* __restrict__ b2g,
    float* __restrict__ out) {
  __shared__ __align__(16) u16 Wst[3][32 * 128];   // 24576 B (triple buffer)
  __shared__ __align__(16) u16 h1c[128 * H1STR];   // 10240 B
  __shared__ float alphS[2][128];                  // 1024 B  (total 35840 B)

  const int tid = threadIdx.x;
  const int wave = tid >> 6, lane = tid & 63;
  const int lnm = lane & 15, lnq = lane >> 4;
  const int rb = blockIdx.x >> 2, sg = blockIdx.x & 3;
  const int row0 = rb * 128, sbase = sg * 2;

  {
    int j = tid >> 7, r = tid & 127;
    alphS[j][r] = alphT[(size_t)(sbase + j) * NROWS + row0 + r];
  }

  float b2v[2];
#pragma unroll
  for (int j = 0; j < 2; j++) b2v[j] = (lnm < NT) ? b2g[(sbase + j) * NT + lnm] : 0.f;

  // stationary B-operand: h0 = relu(enc) bf16, 2 tiles x 16 k-steps = 128 VGPR
  bf16x8 efrag[2][16];
#pragma unroll
  for (int t = 0; t < 2; t++) {
    const float* rp = enc + (size_t)(row0 + wave * 32 + t * 16 + lnm) * H + lnq * 8;
#pragma unroll
    for (int ks = 0; ks < 16; ks++) {
      float4 x0 = *(const float4*)(rp + ks * 32);
      float4 x1 = *(const float4*)(rp + ks * 32 + 4);
      bf16x8 a;
      a[0] = (__bf16)fmaxf(x0.x, 0.f); a[1] = (__bf16)fmaxf(x0.y, 0.f);
      a[2] = (__bf16)fmaxf(x0.z, 0.f); a[3] = (__bf16)fmaxf(x0.w, 0.f);
      a[4] = (__bf16)fmaxf(x1.x, 0.f); a[5] = (__bf16)fmaxf(x1.y, 0.f);
      a[6] = (__bf16)fmaxf(x1.z, 0.f); a[7] = (__bf16)fmaxf(x1.w, 0.f);
      efrag[t][ks] = a;
    }
  }

  // make alphS writes visible before switching to raw s_barrier sync
  // (also drains the VMEM FIFO: only stage(0) outstanding after this)
  __syncthreads();

  const u16* W1g = W1T + (size_t)sbase * 512 * 512;
  stageW8(chunk_base(W1g, 0), Wst[0], tid);
  int cb = 0;
  f32x4 acc[2][2];
  float fin[2][4] = {};
#pragma unroll 1
  for (int j = 0; j < 2; j++) {
    const int s = sbase + j;
    f32x4 oacc[2] = {};
#pragma unroll 1
    for (int wc = 0; wc < 16; wc++) {
      // hoisted epilogue operands — issued BEFORE this wc's stages
      float4 bq0 = *(const float4*)&b1g[s * H + wc * 32 + lnq * 4];
      float4 bq1 = *(const float4*)&b1g[s * H + wc * 32 + 16 + lnq * 4];
      bf16x8 bw = *(const bf16x8*)&W2T[((size_t)s * 16 + lnm) * H + wc * 32 + lnq * 8];
      asm volatile("" ::: "memory");   // pin issue order: epi loads stay at wc-top
#pragma unroll
      for (int t = 0; t < 2; t++) { acc[t][0] = (f32x4){0,0,0,0}; acc[t][1] = (f32x4){0,0,0,0}; }
      KQ_PHASE(0, "5")
      KQ_PHASE(1, "2")
      KQ_PHASE(2, "2")
      KQ_PHASE(3, "2")
      // ---- epilogue: h1 = relu(acc + b1) -> wave-private h1c rows (packed b64) ----
#pragma unroll
      for (int ct = 0; ct < 2; ct++) {
        float4 bq = ct ? bq1 : bq0;
#pragma unroll
        for (int t = 0; t < 2; t++) {
          union { u16 u[4]; uint2 v; } pk;
          pk.u[0] = f2bf(fmaxf(acc[t][ct][0] + bq.x, 0.f));
          pk.u[1] = f2bf(fmaxf(acc[t][ct][1] + bq.y, 0.f));
          pk.u[2] = f2bf(fmaxf(acc[t][ct][2] + bq.z, 0.f));
          pk.u[3] = f2bf(fmaxf(acc[t][ct][3] + bq.w, 0.f));
          *(uint2*)&h1c[(wave * 32 + t * 16 + lnm) * H1STR + ct * 16 + lnq * 4] = pk.v;
        }
      }
      // ---- GEMM2 partial over this 32-wcol window (wave-private, no barrier) ----
      {
#pragma unroll
        for (int t = 0; t < 2; t++) {
          bf16x8 a2 = *(const bf16x8*)&h1c[(wave * 32 + t * 16 + lnm) * H1STR + lnq * 8];
          oacc[t] = __builtin_amdgcn_mfma_f32_16x16x32_bf16(a2, bw, oacc[t], 0, 0, 0);
        }
      }
    }
    // ---- end of source: sigmoid + alpha-weighted accumulate ----
    {
#pragma unroll
      for (int t = 0; t < 2; t++) {
#pragma unroll
        for (int g = 0; g < 4; g++) {
          float sig = 1.f / (1.f + __expf(-(oacc[t][g] + b2v[j])));
          fin[t][g] += alphS[j][wave * 32 + t * 16 + lnq * 4 + g] * sig;
        }
      }
    }
  }
  // combine partials across the 4 source-groups
  if (lnm < NT) {
#pragma unroll
    for (int t = 0; t < 2; t++) {
#pragma unroll
      for (int g = 0; g < 4; g++) {
        int rg = row0 + wave * 32 + t * 16 + lnq * 4 + g;
        atomicAdd(&out[(size_t)rg * NT + lnm], fin[t][g]);
      }
    }
  }
}

extern "C" void kernel_launch(void* const* d_in, const int* in_sizes, int n_in,
                              void* d_out, int out_size, void* d_ws, size_t ws_size,
                              hipStream_t stream) {
  const float* enc = (const float*)d_in[0];
  const float* mu  = (const float*)d_in[1];
  const float* Us  = (const float*)d_in[2];
  const float* W1  = (const float*)d_in[3];
  const float* b1  = (const float*)d_in[4];
  const float* W2  = (const float*)d_in[5];
  const float* b2  = (const float*)d_in[6];
  float* out = (float*)d_out;
  char* ws = (char*)d_ws;
  u16* W1T    = (u16*)(ws + WS_W1T);
  u16* UcatT  = (u16*)(ws + WS_UCT);
  u16* W2T    = (u16*)(ws + WS_W2T);
  float* cvec = (float*)(ws + WS_CVEC);
  float* alphT = (float*)(ws + WS_ALPH);

  prep<<<2560, dim3(32, 8, 1), 0, stream>>>(W1, W1T, Us, UcatT, W2, W2T, mu, cvec);
  routing<<<512, 256, 0, stream>>>(enc, UcatT, cvec, alphT);
  hipMemsetAsync(out, 0, (size_t)out_size * sizeof(float), stream);
  moe_main<<<1024, 256, 0, stream>>>(enc, W1T, W2T, alphT, b1, b2, out);
}

// Round 10
// 273.139 us; speedup vs baseline: 1.1848x; 1.1848x over previous
//
#include <hip/hip_runtime.h>
#include <hip/hip_bf16.h>

typedef unsigned short u16;
typedef __bf16 bf16x8 __attribute__((ext_vector_type(8)));
typedef float f32x4 __attribute__((ext_vector_type(4)));

#define NROWS 32768
#define H 512
#define NS 8
#define NR 64
#define NT 12

// workspace layout (bytes)
#define WS_W1T   0            // [8][512 n][512 k] bf16 = 4194304
#define WS_UCT   4194304      // [512 r][512 k] bf16    = 524288
#define WS_W2T   4718592      // [8][16 t][512 k] bf16  = 131072
#define WS_CVEC  4849664      // [8][64] f32            = 2048
#define WS_ALPH  4851712      // [8][32768] f32         = 1048576

union BFU { __bf16 h; u16 u; };
__device__ __forceinline__ u16 f2bf(float v) { BFU b; b.h = (__bf16)v; return b.u; }

__device__ __forceinline__ void gload16(const u16* g, u16* l) {
  __builtin_amdgcn_global_load_lds(
      (const __attribute__((address_space(1))) unsigned int*)g,
      (__attribute__((address_space(3))) unsigned int*)l, 16, 0, 0);
}

// ---------- fused prep: 3 transposes + compute_c in one launch ----------
__global__ __launch_bounds__(256) void prep(
    const float* __restrict__ W1, u16* __restrict__ W1T,
    const float* __restrict__ Us, u16* __restrict__ UcatT,
    const float* __restrict__ W2, u16* __restrict__ W2T,
    const float* __restrict__ mu, float* __restrict__ cvec) {
  __shared__ float tile[32][33];
  const int bid = blockIdx.x;
  const int tx = threadIdx.x, ty = threadIdx.y;
  if (bid < 2432) {
    const float* in; u16* out; int Rr, Cc, Cpad, b, r0, c0;
    if (bid < 2048) {
      in = W1; out = W1T; Rr = 512; Cc = 512; Cpad = 512;
      r0 = (bid & 15) * 32; c0 = ((bid >> 4) & 15) * 32; b = bid >> 8;
    } else if (bid < 2304) {
      int t2 = bid - 2048; in = Us; out = UcatT; Rr = 512; Cc = 64; Cpad = 64;
      r0 = (t2 & 15) * 32; c0 = ((t2 >> 4) & 1) * 32; b = t2 >> 5;
    } else {
      int t2 = bid - 2304; in = W2; out = W2T; Rr = 512; Cc = 12; Cpad = 16;
      r0 = (t2 & 15) * 32; c0 = 0; b = t2 >> 4;
    }
#pragma unroll
    for (int i = 0; i < 4; i++) {
      int r = r0 + ty + i * 8, c = c0 + tx;
      float v = 0.f;
      if (r < Rr && c < Cc) v = in[((size_t)b * Rr + r) * Cc + c];
      tile[ty + i * 8][tx] = v;
    }
    __syncthreads();
#pragma unroll
    for (int i = 0; i < 4; i++) {
      int c = c0 + ty + i * 8, r = r0 + tx;
      if (c < Cpad && r < Rr) out[((size_t)b * Cpad + c) * Rr + r] = f2bf(tile[tx][ty + i * 8]);
    }
  } else {
    const int tid = ty * 32 + tx;
    const int idx = (bid - 2432) * 4 + (tid >> 6);   // (s,r) pair, 0..511
    const int s = idx >> 6, r = idx & 63, t = tid & 63;
    float acc = 0.f;
#pragma unroll
    for (int k = t; k < H; k += 64) acc += mu[s * H + k] * Us[((size_t)s * H + k) * NR + r];
#pragma unroll
    for (int m = 32; m; m >>= 1) acc += __shfl_xor(acc, m, 64);
    if (t == 0) cvec[idx] = acc;
  }
}

// ---------- shared staging helper: 32 rows x 256 u16, src row stride 512 ----------
__device__ __forceinline__ void stageW16(const u16* __restrict__ g, u16* l, int tid) {
#pragma unroll
  for (int i = 0; i < 4; i++) {
    int flat = tid + i * 256;          // 0..1023
    int r = flat >> 5, u = flat & 31;
    gload16(g + (size_t)r * 512 + (u ^ (r & 7)) * 8, l + flat * 8);
  }
}

// ---------- routing: 512 blocks x 64 rows, moe_main pipeline ----------
// Same math/reduction order as the round-0 known-good; only the staging
// machinery changes: 16 KB chunks (32 rcols x 256 K) triple-buffered,
// counted-vmcnt own-stage-retire, ONE raw barrier per phase (32 phases),
// cvec pre-staged to LDS (no mid-loop scalar VMEM).
__global__ __launch_bounds__(256, 2) void routing(
    const float* __restrict__ enc, const u16* __restrict__ UcatT,
    const float* __restrict__ cvec, float* __restrict__ alphT) {
  __shared__ __align__(16) u16 Wst[3][32 * 256];   // 49152 B
  __shared__ float distS[NS][64];                  // 2048 B
  __shared__ float cvS[512];                       // 2048 B (total 53248)

  const int tid = threadIdx.x;
  const int wave = tid >> 6, lane = tid & 63;
  const int lnm = lane & 15, lnq = lane >> 4;
  const int row0 = blockIdx.x * 64;

  cvS[tid] = cvec[tid];
  cvS[256 + tid] = cvec[256 + tid];

  // stationary A-operand: raw enc, 16 k-steps = 64 VGPR
  bf16x8 afrag[16];
  {
    const float* rp = enc + (size_t)(row0 + wave * 16 + lnm) * H + lnq * 8;
#pragma unroll
    for (int ks = 0; ks < 16; ks++) {
      float4 x0 = *(const float4*)(rp + ks * 32);
      float4 x1 = *(const float4*)(rp + ks * 32 + 4);
      bf16x8 a;
      a[0] = (__bf16)x0.x; a[1] = (__bf16)x0.y; a[2] = (__bf16)x0.z; a[3] = (__bf16)x0.w;
      a[4] = (__bf16)x1.x; a[5] = (__bf16)x1.y; a[6] = (__bf16)x1.z; a[7] = (__bf16)x1.w;
      afrag[ks] = a;
    }
  }

  __syncthreads();   // cvS visible; VMEM FIFO drained before raw-barrier loop

  stageW16(UcatT, Wst[0], tid);   // chunk 0: rcols 0..31, K 0..255
  int cb = 0;
  float dsq[4] = {0.f, 0.f, 0.f, 0.f};
#pragma unroll 1
  for (int wcw = 0; wcw < 16; wcw++) {   // 32-rcol windows
    f32x4 acc[2] = {};
#pragma unroll
    for (int kh = 0; kh < 2; kh++) {
      const int q = wcw * 2 + kh;
      const int nb = (cb == 2) ? 0 : cb + 1;
      if (q + 1 < 32) {
        stageW16(UcatT + (size_t)((q + 1) >> 1) * 32 * 512 + ((q + 1) & 1) * 256, Wst[nb], tid);
        asm volatile("s_waitcnt vmcnt(4)" ::: "memory");  // own stage(q) retired
      } else {
        asm volatile("s_waitcnt vmcnt(0)" ::: "memory");
      }
      __builtin_amdgcn_s_barrier();
      const u16* buf = Wst[cb];
      __builtin_amdgcn_s_setprio(1);
#pragma unroll
      for (int ks = 0; ks < 8; ks++) {
        const int uu = ((ks * 4 + lnq) ^ (lnm & 7)) * 8;
        bf16x8 b0 = *(const bf16x8*)&buf[lnm * 256 + uu];
        bf16x8 b1v = *(const bf16x8*)&buf[(16 + lnm) * 256 + uu];
        acc[0] = __builtin_amdgcn_mfma_f32_16x16x32_bf16(afrag[kh * 8 + ks], b0, acc[0], 0, 0, 0);
        acc[1] = __builtin_amdgcn_mfma_f32_16x16x32_bf16(afrag[kh * 8 + ks], b1v, acc[1], 0, 0, 0);
      }
      __builtin_amdgcn_s_setprio(0);
      cb = nb;
    }
    // window epilogue: rcols wcw*32 + ct*16 + lnm
#pragma unroll
    for (int ct = 0; ct < 2; ct++) {
      float cv = cvS[wcw * 32 + ct * 16 + lnm];
#pragma unroll
      for (int g = 0; g < 4; g++) { float d = acc[ct][g] - cv; dsq[g] += d * d; }
    }
    if (wcw & 1) {   // source s = wcw>>1 complete (64 rcols)
#pragma unroll
      for (int m = 1; m < 16; m <<= 1) {
#pragma unroll
        for (int g = 0; g < 4; g++) dsq[g] += __shfl_xor(dsq[g], m, 16);
      }
      if (lnm == 0) {
#pragma unroll
        for (int g = 0; g < 4; g++) distS[wcw >> 1][wave * 16 + lnq * 4 + g] = sqrtf(dsq[g]);
      }
#pragma unroll
      for (int g = 0; g < 4; g++) dsq[g] = 0.f;
    }
  }
  __syncthreads();
  if (tid < 64) {
    float dmin = distS[0][tid];
#pragma unroll
    for (int s = 1; s < NS; s++) dmin = fminf(dmin, distS[s][tid]);
    float den = 0.f, e[NS];
#pragma unroll
    for (int s = 0; s < NS; s++) { e[s] = __expf(dmin - distS[s][tid]); den += e[s]; }
    float inv = 1.f / den;
#pragma unroll
    for (int s = 0; s < NS; s++) alphT[(size_t)s * NROWS + row0 + tid] = e[s] * inv;
  }
}

// ---------- main classifier (round-6 proven 157us config, verbatim) ----------
// Grid: 512 blocks = 256 row-blocks (128 rows) x 2 source-groups (4 sources).
// Triple-buffered 16 KB chunks, counted-vmcnt single barrier per half-chunk,
// hoisted epilogue operands.  FIFO: wc-top 3 epi loads; kh0 +4 stage ->
// vmcnt(7) retires stage(q); kh1 +4 stage -> vmcnt(4) retires epi+stage(q+1).
#define H1STR 40   // u16 row stride (80 B)

// chunk index q in [0,128): j=q>>5 (source), wc=(q>>1)&15, kh=q&1
__device__ __forceinline__ const u16* chunk_base(const u16* W1g, int q) {
  return W1g + ((size_t)(q >> 5) * 512 + ((q >> 1) & 15) * 32) * 512 + (q & 1) * 256;
}

__global__ __launch_bounds__(256, 2) void moe_main(
    const float* __restrict__ enc, const u16* __restrict__ W1T,
    const u16* __restrict__ W2T, const float* __restrict__ alphT,
    const float* __restrict__ b1g, const float* __restrict__ b2g,
    float* __restrict__ out) {
  __shared__ __align__(16) u16 Wst[3][32 * 256];   // 49152 B (triple buffer)
  __shared__ __align__(16) u16 h1c[128 * H1STR];   // 10240 B
  __shared__ float alphS[4][128];                  // 2048 B  (total 61440 B)

  const int tid = threadIdx.x;
  const int wave = tid >> 6, lane = tid & 63;
  const int lnm = lane & 15, lnq = lane >> 4;
  const int rb = blockIdx.x >> 1, sg = blockIdx.x & 1;
  const int row0 = rb * 128, sbase = sg * 4;

#pragma unroll
  for (int i = 0; i < 2; i++) {
    int u = tid + i * 256, j = u >> 7, r = u & 127;
    alphS[j][r] = alphT[(size_t)(sbase + j) * NROWS + row0 + r];
  }

  float b2v[4];
#pragma unroll
  for (int j = 0; j < 4; j++) b2v[j] = (lnm < NT) ? b2g[(sbase + j) * NT + lnm] : 0.f;

  // stationary B-operand: h0 = relu(enc) bf16, 2 tiles x 16 k-steps = 128 VGPR
  bf16x8 efrag[2][16];
#pragma unroll
  for (int t = 0; t < 2; t++) {
    const float* rp = enc + (size_t)(row0 + wave * 32 + t * 16 + lnm) * H + lnq * 8;
#pragma unroll
    for (int ks = 0; ks < 16; ks++) {
      float4 x0 = *(const float4*)(rp + ks * 32);
      float4 x1 = *(const float4*)(rp + ks * 32 + 4);
      bf16x8 a;
      a[0] = (__bf16)fmaxf(x0.x, 0.f); a[1] = (__bf16)fmaxf(x0.y, 0.f);
      a[2] = (__bf16)fmaxf(x0.z, 0.f); a[3] = (__bf16)fmaxf(x0.w, 0.f);
      a[4] = (__bf16)fmaxf(x1.x, 0.f); a[5] = (__bf16)fmaxf(x1.y, 0.f);
      a[6] = (__bf16)fmaxf(x1.z, 0.f); a[7] = (__bf16)fmaxf(x1.w, 0.f);
      efrag[t][ks] = a;
    }
  }

  // make alphS writes visible before switching to raw s_barrier sync
  __syncthreads();

  const u16* W1g = W1T + (size_t)sbase * 512 * 512;
  stageW16(chunk_base(W1g, 0), Wst[0], tid);
  int cb = 0;
  f32x4 acc[2][2];
  float fin[2][4] = {};
#pragma unroll 1
  for (int j = 0; j < 4; j++) {
    const int s = sbase + j;
    f32x4 oacc[2] = {};
#pragma unroll 1
    for (int wc = 0; wc < 16; wc++) {
      const int q = j * 32 + wc * 2;
      // hoisted epilogue operands — issued BEFORE this wc's stages
      float4 bq0 = *(const float4*)&b1g[s * H + wc * 32 + lnq * 4];
      float4 bq1 = *(const float4*)&b1g[s * H + wc * 32 + 16 + lnq * 4];
      bf16x8 bw = *(const bf16x8*)&W2T[((size_t)s * 16 + lnm) * H + wc * 32 + lnq * 8];
      asm volatile("" ::: "memory");   // pin issue order: loads stay at wc-top
      // ======== kh = 0 : compute chunk q from Wst[cb] ========
      {
        const int nb = (cb == 2) ? 0 : cb + 1;
        stageW16(chunk_base(W1g, q + 1), Wst[nb], tid);   // q+1 <= 127 always
        asm volatile("s_waitcnt vmcnt(7)" ::: "memory");  // retires stage(q); keeps epi + stage(q+1)
        __builtin_amdgcn_s_barrier();
        const u16* buf = Wst[cb];
#pragma unroll
        for (int t = 0; t < 2; t++) { acc[t][0] = (f32x4){0,0,0,0}; acc[t][1] = (f32x4){0,0,0,0}; }
        __builtin_amdgcn_s_setprio(1);
#pragma unroll
        for (int ks = 0; ks < 8; ks++) {
          const int uu = ((ks * 4 + lnq) ^ (lnm & 7)) * 8;
          bf16x8 w0 = *(const bf16x8*)&buf[lnm * 256 + uu];
          bf16x8 w1 = *(const bf16x8*)&buf[(16 + lnm) * 256 + uu];
#pragma unroll
          for (int t = 0; t < 2; t++) {
            acc[t][0] = __builtin_amdgcn_mfma_f32_16x16x32_bf16(w0, efrag[t][ks], acc[t][0], 0, 0, 0);
            acc[t][1] = __builtin_amdgcn_mfma_f32_16x16x32_bf16(w1, efrag[t][ks], acc[t][1], 0, 0, 0);
          }
        }
        __builtin_amdgcn_s_setprio(0);
        cb = nb;
      }
      // ======== kh = 1 : compute chunk q+1 from Wst[cb] ========
      {
        const int nb = (cb == 2) ? 0 : cb + 1;
        if (q + 2 < 128) {
          stageW16(chunk_base(W1g, q + 2), Wst[nb], tid);
          asm volatile("s_waitcnt vmcnt(4)" ::: "memory");  // retires epi + stage(q+1)
        } else {
          asm volatile("s_waitcnt vmcnt(0)" ::: "memory");  // last chunk: drain
        }
        __builtin_amdgcn_s_barrier();
        const u16* buf = Wst[cb];
        __builtin_amdgcn_s_setprio(1);
#pragma unroll
        for (int ks = 0; ks < 8; ks++) {
          const int uu = ((ks * 4 + lnq) ^ (lnm & 7)) * 8;
          bf16x8 w0 = *(const bf16x8*)&buf[lnm * 256 + uu];
          bf16x8 w1 = *(const bf16x8*)&buf[(16 + lnm) * 256 + uu];
#pragma unroll
          for (int t = 0; t < 2; t++) {
            acc[t][0] = __builtin_amdgcn_mfma_f32_16x16x32_bf16(w0, efrag[t][8 + ks], acc[t][0], 0, 0, 0);
            acc[t][1] = __builtin_amdgcn_mfma_f32_16x16x32_bf16(w1, efrag[t][8 + ks], acc[t][1], 0, 0, 0);
          }
        }
        __builtin_amdgcn_s_setprio(0);
        cb = nb;
      }
      // ---- epilogue: h1 = relu(acc + b1) -> wave-private h1c rows (packed b64) ----
#pragma unroll
      for (int ct = 0; ct < 2; ct++) {
        float4 bq = ct ? bq1 : bq0;
#pragma unroll
        for (int t = 0; t < 2; t++) {
          union { u16 u[4]; uint2 v; } pk;
          pk.u[0] = f2bf(fmaxf(acc[t][ct][0] + bq.x, 0.f));
          pk.u[1] = f2bf(fmaxf(acc[t][ct][1] + bq.y, 0.f));
          pk.u[2] = f2bf(fmaxf(acc[t][ct][2] + bq.z, 0.f));
          pk.u[3] = f2bf(fmaxf(acc[t][ct][3] + bq.w, 0.f));
          *(uint2*)&h1c[(wave * 32 + t * 16 + lnm) * H1STR + ct * 16 + lnq * 4] = pk.v;
        }
      }
      // ---- GEMM2 partial over this 32-wcol window (wave-private, no barrier) ----
      {
#pragma unroll
        for (int t = 0; t < 2; t++) {
          bf16x8 a2 = *(const bf16x8*)&h1c[(wave * 32 + t * 16 + lnm) * H1STR + lnq * 8];
          oacc[t] = __builtin_amdgcn_mfma_f32_16x16x32_bf16(a2, bw, oacc[t], 0, 0, 0);
        }
      }
    }
    // ---- end of source: sigmoid + alpha-weighted accumulate ----
    {
#pragma unroll
      for (int t = 0; t < 2; t++) {
#pragma unroll
        for (int g = 0; g < 4; g++) {
          float sig = 1.f / (1.f + __expf(-(oacc[t][g] + b2v[j])));
          fin[t][g] += alphS[j][wave * 32 + t * 16 + lnq * 4 + g] * sig;
        }
      }
    }
  }
  // combine partials across the 2 source-groups
  if (lnm < NT) {
#pragma unroll
    for (int t = 0; t < 2; t++) {
#pragma unroll
      for (int g = 0; g < 4; g++) {
        int rg = row0 + wave * 32 + t * 16 + lnq * 4 + g;
        atomicAdd(&out[(size_t)rg * NT + lnm], fin[t][g]);
      }
    }
  }
}

extern "C" void kernel_launch(void* const* d_in, const int* in_sizes, int n_in,
                              void* d_out, int out_size, void* d_ws, size_t ws_size,
                              hipStream_t stream) {
  const float* enc = (const float*)d_in[0];
  const float* mu  = (const float*)d_in[1];
  const float* Us  = (const float*)d_in[2];
  const float* W1  = (const float*)d_in[3];
  const float* b1  = (const float*)d_in[4];
  const float* W2  = (const float*)d_in[5];
  const float* b2  = (const float*)d_in[6];
  float* out = (float*)d_out;
  char* ws = (char*)d_ws;
  u16* W1T    = (u16*)(ws + WS_W1T);
  u16* UcatT  = (u16*)(ws + WS_UCT);
  u16* W2T    = (u16*)(ws + WS_W2T);
  float* cvec = (float*)(ws + WS_CVEC);
  float* alphT = (float*)(ws + WS_ALPH);

  prep<<<2560, dim3(32, 8, 1), 0, stream>>>(W1, W1T, Us, UcatT, W2, W2T, mu, cvec);
  routing<<<512, 256, 0, stream>>>(enc, UcatT, cvec, alphT);
  hipMemsetAsync(out, 0, (size_t)out_size * sizeof(float), stream);
  moe_main<<<512, 256, 0, stream>>>(enc, W1T, W2T, alphT, b1, b2, out);
}

// Round 11
// 270.077 us; speedup vs baseline: 1.1982x; 1.0113x over previous
//
#include <hip/hip_runtime.h>
#include <hip/hip_bf16.h>

typedef unsigned short u16;
typedef __bf16 bf16x8 __attribute__((ext_vector_type(8)));
typedef float f32x4 __attribute__((ext_vector_type(4)));

#define NROWS 32768
#define H 512
#define NS 8
#define NR 64
#define NT 12

// workspace layout (bytes)
#define WS_W1T   0            // [8][512 n][512 k] bf16 = 4194304
#define WS_UCT   4194304      // [512 r][512 k] bf16    = 524288
#define WS_W2T   4718592      // [8][16 t][512 k] bf16  = 131072
#define WS_CVEC  4849664      // [8][64] f32            = 2048
#define WS_ALPH  4851712      // [8][32768] f32         = 1048576

union BFU { __bf16 h; u16 u; };
__device__ __forceinline__ u16 f2bf(float v) { BFU b; b.h = (__bf16)v; return b.u; }

__device__ __forceinline__ void gload16(const u16* g, u16* l) {
  __builtin_amdgcn_global_load_lds(
      (const __attribute__((address_space(1))) unsigned int*)g,
      (__attribute__((address_space(3))) unsigned int*)l, 16, 0, 0);
}

// ---------- fused prep: 3 transposes + compute_c in one launch ----------
__global__ __launch_bounds__(256) void prep(
    const float* __restrict__ W1, u16* __restrict__ W1T,
    const float* __restrict__ Us, u16* __restrict__ UcatT,
    const float* __restrict__ W2, u16* __restrict__ W2T,
    const float* __restrict__ mu, float* __restrict__ cvec) {
  __shared__ float tile[32][33];
  const int bid = blockIdx.x;
  const int tx = threadIdx.x, ty = threadIdx.y;
  if (bid < 2432) {
    const float* in; u16* out; int Rr, Cc, Cpad, b, r0, c0;
    if (bid < 2048) {
      in = W1; out = W1T; Rr = 512; Cc = 512; Cpad = 512;
      r0 = (bid & 15) * 32; c0 = ((bid >> 4) & 15) * 32; b = bid >> 8;
    } else if (bid < 2304) {
      int t2 = bid - 2048; in = Us; out = UcatT; Rr = 512; Cc = 64; Cpad = 64;
      r0 = (t2 & 15) * 32; c0 = ((t2 >> 4) & 1) * 32; b = t2 >> 5;
    } else {
      int t2 = bid - 2304; in = W2; out = W2T; Rr = 512; Cc = 12; Cpad = 16;
      r0 = (t2 & 15) * 32; c0 = 0; b = t2 >> 4;
    }
#pragma unroll
    for (int i = 0; i < 4; i++) {
      int r = r0 + ty + i * 8, c = c0 + tx;
      float v = 0.f;
      if (r < Rr && c < Cc) v = in[((size_t)b * Rr + r) * Cc + c];
      tile[ty + i * 8][tx] = v;
    }
    __syncthreads();
#pragma unroll
    for (int i = 0; i < 4; i++) {
      int c = c0 + ty + i * 8, r = r0 + tx;
      if (c < Cpad && r < Rr) out[((size_t)b * Cpad + c) * Rr + r] = f2bf(tile[tx][ty + i * 8]);
    }
  } else {
    const int tid = ty * 32 + tx;
    const int idx = (bid - 2432) * 4 + (tid >> 6);   // (s,r) pair, 0..511
    const int s = idx >> 6, r = idx & 63, t = tid & 63;
    float acc = 0.f;
#pragma unroll
    for (int k = t; k < H; k += 64) acc += mu[s * H + k] * Us[((size_t)s * H + k) * NR + r];
#pragma unroll
    for (int m = 32; m; m >>= 1) acc += __shfl_xor(acc, m, 64);
    if (t == 0) cvec[idx] = acc;
  }
}

// ---------- shared staging helper: 32 rows x 256 u16, src row stride 512 ----------
__device__ __forceinline__ void stageW16(const u16* __restrict__ g, u16* l, int tid) {
#pragma unroll
  for (int i = 0; i < 4; i++) {
    int flat = tid + i * 256;          // 0..1023
    int r = flat >> 5, u = flat & 31;
    gload16(g + (size_t)r * 512 + (u ^ (r & 7)) * 8, l + flat * 8);
  }
}

// ---------- routing: 512 blocks x 64 rows, counted-vmcnt pipeline ----------
// (r10 structure; setprio removed — m190: setprio costs ~1.5% on lockstep
// 2-barrier structures; its gains require 8-phase role-split we don't have.)
__global__ __launch_bounds__(256, 2) void routing(
    const float* __restrict__ enc, const u16* __restrict__ UcatT,
    const float* __restrict__ cvec, float* __restrict__ alphT) {
  __shared__ __align__(16) u16 Wst[3][32 * 256];   // 49152 B
  __shared__ float distS[NS][64];                  // 2048 B
  __shared__ float cvS[512];                       // 2048 B (total 53248)

  const int tid = threadIdx.x;
  const int wave = tid >> 6, lane = tid & 63;
  const int lnm = lane & 15, lnq = lane >> 4;
  const int row0 = blockIdx.x * 64;

  cvS[tid] = cvec[tid];
  cvS[256 + tid] = cvec[256 + tid];

  // stationary A-operand: raw enc, 16 k-steps = 64 VGPR
  bf16x8 afrag[16];
  {
    const float* rp = enc + (size_t)(row0 + wave * 16 + lnm) * H + lnq * 8;
#pragma unroll
    for (int ks = 0; ks < 16; ks++) {
      float4 x0 = *(const float4*)(rp + ks * 32);
      float4 x1 = *(const float4*)(rp + ks * 32 + 4);
      bf16x8 a;
      a[0] = (__bf16)x0.x; a[1] = (__bf16)x0.y; a[2] = (__bf16)x0.z; a[3] = (__bf16)x0.w;
      a[4] = (__bf16)x1.x; a[5] = (__bf16)x1.y; a[6] = (__bf16)x1.z; a[7] = (__bf16)x1.w;
      afrag[ks] = a;
    }
  }

  __syncthreads();   // cvS visible; VMEM FIFO drained before raw-barrier loop

  stageW16(UcatT, Wst[0], tid);   // chunk 0: rcols 0..31, K 0..255
  int cb = 0;
  float dsq[4] = {0.f, 0.f, 0.f, 0.f};
#pragma unroll 1
  for (int wcw = 0; wcw < 16; wcw++) {   // 32-rcol windows
    f32x4 acc[2] = {};
#pragma unroll
    for (int kh = 0; kh < 2; kh++) {
      const int q = wcw * 2 + kh;
      const int nb = (cb == 2) ? 0 : cb + 1;
      if (q + 1 < 32) {
        stageW16(UcatT + (size_t)((q + 1) >> 1) * 32 * 512 + ((q + 1) & 1) * 256, Wst[nb], tid);
        asm volatile("s_waitcnt vmcnt(4)" ::: "memory");  // own stage(q) retired
      } else {
        asm volatile("s_waitcnt vmcnt(0)" ::: "memory");
      }
      __builtin_amdgcn_s_barrier();
      const u16* buf = Wst[cb];
#pragma unroll
      for (int ks = 0; ks < 8; ks++) {
        const int uu = ((ks * 4 + lnq) ^ (lnm & 7)) * 8;
        bf16x8 b0 = *(const bf16x8*)&buf[lnm * 256 + uu];
        bf16x8 b1v = *(const bf16x8*)&buf[(16 + lnm) * 256 + uu];
        acc[0] = __builtin_amdgcn_mfma_f32_16x16x32_bf16(afrag[kh * 8 + ks], b0, acc[0], 0, 0, 0);
        acc[1] = __builtin_amdgcn_mfma_f32_16x16x32_bf16(afrag[kh * 8 + ks], b1v, acc[1], 0, 0, 0);
      }
      cb = nb;
    }
    // window epilogue: rcols wcw*32 + ct*16 + lnm
#pragma unroll
    for (int ct = 0; ct < 2; ct++) {
      float cv = cvS[wcw * 32 + ct * 16 + lnm];
#pragma unroll
      for (int g = 0; g < 4; g++) { float d = acc[ct][g] - cv; dsq[g] += d * d; }
    }
    if (wcw & 1) {   // source s = wcw>>1 complete (64 rcols)
#pragma unroll
      for (int m = 1; m < 16; m <<= 1) {
#pragma unroll
        for (int g = 0; g < 4; g++) dsq[g] += __shfl_xor(dsq[g], m, 16);
      }
      if (lnm == 0) {
#pragma unroll
        for (int g = 0; g < 4; g++) distS[wcw >> 1][wave * 16 + lnq * 4 + g] = sqrtf(dsq[g]);
      }
#pragma unroll
      for (int g = 0; g < 4; g++) dsq[g] = 0.f;
    }
  }
  __syncthreads();
  if (tid < 64) {
    float dmin = distS[0][tid];
#pragma unroll
    for (int s = 1; s < NS; s++) dmin = fminf(dmin, distS[s][tid]);
    float den = 0.f, e[NS];
#pragma unroll
    for (int s = 0; s < NS; s++) { e[s] = __expf(dmin - distS[s][tid]); den += e[s]; }
    float inv = 1.f / den;
#pragma unroll
    for (int s = 0; s < NS; s++) alphT[(size_t)s * NROWS + row0 + tid] = e[s] * inv;
  }
}

// ---------- main classifier (r10 structure; setprio removed, bias-folded) ----------
// Grid: 512 blocks = 256 row-blocks (128 rows) x 2 source-groups (4 sources).
// Triple-buffered 16 KB chunks, counted-vmcnt single barrier per half-chunk,
// hoisted epilogue operands.  FIFO: wc-top 3 epi loads; kh0 +4 stage ->
// vmcnt(7) retires stage(q); kh1 +4 stage -> vmcnt(4) retires epi+stage(q+1).
// NEW: b1 folded into acc init (acc starts at bias; epilogue drops the add).
// bq is >=600cyc old at the post-barrier init, so the implicit wait retires
// only bq0/bq1 (vmcnt(5)-equivalent), keeping bw + stage(q+1) in flight.
#define H1STR 40   // u16 row stride (80 B)

// chunk index q in [0,128): j=q>>5 (source), wc=(q>>1)&15, kh=q&1
__device__ __forceinline__ const u16* chunk_base(const u16* W1g, int q) {
  return W1g + ((size_t)(q >> 5) * 512 + ((q >> 1) & 15) * 32) * 512 + (q & 1) * 256;
}

__global__ __launch_bounds__(256, 2) void moe_main(
    const float* __restrict__ enc, const u16* __restrict__ W1T,
    const u16* __restrict__ W2T, const float* __restrict__ alphT,
    const float* __restrict__ b1g, const float* __restrict__ b2g,
    float* __restrict__ out) {
  __shared__ __align__(16) u16 Wst[3][32 * 256];   // 49152 B (triple buffer)
  __shared__ __align__(16) u16 h1c[128 * H1STR];   // 10240 B
  __shared__ float alphS[4][128];                  // 2048 B  (total 61440 B)

  const int tid = threadIdx.x;
  const int wave = tid >> 6, lane = tid & 63;
  const int lnm = lane & 15, lnq = lane >> 4;
  const int rb = blockIdx.x >> 1, sg = blockIdx.x & 1;
  const int row0 = rb * 128, sbase = sg * 4;

#pragma unroll
  for (int i = 0; i < 2; i++) {
    int u = tid + i * 256, j = u >> 7, r = u & 127;
    alphS[j][r] = alphT[(size_t)(sbase + j) * NROWS + row0 + r];
  }

  float b2v[4];
#pragma unroll
  for (int j = 0; j < 4; j++) b2v[j] = (lnm < NT) ? b2g[(sbase + j) * NT + lnm] : 0.f;

  // stationary B-operand: h0 = relu(enc) bf16, 2 tiles x 16 k-steps = 128 VGPR
  bf16x8 efrag[2][16];
#pragma unroll
  for (int t = 0; t < 2; t++) {
    const float* rp = enc + (size_t)(row0 + wave * 32 + t * 16 + lnm) * H + lnq * 8;
#pragma unroll
    for (int ks = 0; ks < 16; ks++) {
      float4 x0 = *(const float4*)(rp + ks * 32);
      float4 x1 = *(const float4*)(rp + ks * 32 + 4);
      bf16x8 a;
      a[0] = (__bf16)fmaxf(x0.x, 0.f); a[1] = (__bf16)fmaxf(x0.y, 0.f);
      a[2] = (__bf16)fmaxf(x0.z, 0.f); a[3] = (__bf16)fmaxf(x0.w, 0.f);
      a[4] = (__bf16)fmaxf(x1.x, 0.f); a[5] = (__bf16)fmaxf(x1.y, 0.f);
      a[6] = (__bf16)fmaxf(x1.z, 0.f); a[7] = (__bf16)fmaxf(x1.w, 0.f);
      efrag[t][ks] = a;
    }
  }

  // make alphS writes visible before switching to raw s_barrier sync
  __syncthreads();

  const u16* W1g = W1T + (size_t)sbase * 512 * 512;
  stageW16(chunk_base(W1g, 0), Wst[0], tid);
  int cb = 0;
  f32x4 acc[2][2];
  float fin[2][4] = {};
#pragma unroll 1
  for (int j = 0; j < 4; j++) {
    const int s = sbase + j;
    f32x4 oacc[2] = {};
#pragma unroll 1
    for (int wc = 0; wc < 16; wc++) {
      const int q = j * 32 + wc * 2;
      // hoisted epilogue operands — issued BEFORE this wc's stages
      float4 bq0 = *(const float4*)&b1g[s * H + wc * 32 + lnq * 4];
      float4 bq1 = *(const float4*)&b1g[s * H + wc * 32 + 16 + lnq * 4];
      bf16x8 bw = *(const bf16x8*)&W2T[((size_t)s * 16 + lnm) * H + wc * 32 + lnq * 8];
      asm volatile("" ::: "memory");   // pin issue order: loads stay at wc-top
      // ======== kh = 0 : compute chunk q from Wst[cb] ========
      {
        const int nb = (cb == 2) ? 0 : cb + 1;
        stageW16(chunk_base(W1g, q + 1), Wst[nb], tid);   // q+1 <= 127 always
        asm volatile("s_waitcnt vmcnt(7)" ::: "memory");  // retires stage(q); keeps epi + stage(q+1)
        __builtin_amdgcn_s_barrier();
        const u16* buf = Wst[cb];
        // bias-folded accumulator init (bq retired by implicit wait; bw/stage stay)
#pragma unroll
        for (int t = 0; t < 2; t++) {
          acc[t][0] = (f32x4){bq0.x, bq0.y, bq0.z, bq0.w};
          acc[t][1] = (f32x4){bq1.x, bq1.y, bq1.z, bq1.w};
        }
#pragma unroll
        for (int ks = 0; ks < 8; ks++) {
          const int uu = ((ks * 4 + lnq) ^ (lnm & 7)) * 8;
          bf16x8 w0 = *(const bf16x8*)&buf[lnm * 256 + uu];
          bf16x8 w1 = *(const bf16x8*)&buf[(16 + lnm) * 256 + uu];
#pragma unroll
          for (int t = 0; t < 2; t++) {
            acc[t][0] = __builtin_amdgcn_mfma_f32_16x16x32_bf16(w0, efrag[t][ks], acc[t][0], 0, 0, 0);
            acc[t][1] = __builtin_amdgcn_mfma_f32_16x16x32_bf16(w1, efrag[t][ks], acc[t][1], 0, 0, 0);
          }
        }
        cb = nb;
      }
      // ======== kh = 1 : compute chunk q+1 from Wst[cb] ========
      {
        const int nb = (cb == 2) ? 0 : cb + 1;
        if (q + 2 < 128) {
          stageW16(chunk_base(W1g, q + 2), Wst[nb], tid);
          asm volatile("s_waitcnt vmcnt(4)" ::: "memory");  // retires epi + stage(q+1)
        } else {
          asm volatile("s_waitcnt vmcnt(0)" ::: "memory");  // last chunk: drain
        }
        __builtin_amdgcn_s_barrier();
        const u16* buf = Wst[cb];
#pragma unroll
        for (int ks = 0; ks < 8; ks++) {
          const int uu = ((ks * 4 + lnq) ^ (lnm & 7)) * 8;
          bf16x8 w0 = *(const bf16x8*)&buf[lnm * 256 + uu];
          bf16x8 w1 = *(const bf16x8*)&buf[(16 + lnm) * 256 + uu];
#pragma unroll
          for (int t = 0; t < 2; t++) {
            acc[t][0] = __builtin_amdgcn_mfma_f32_16x16x32_bf16(w0, efrag[t][8 + ks], acc[t][0], 0, 0, 0);
            acc[t][1] = __builtin_amdgcn_mfma_f32_16x16x32_bf16(w1, efrag[t][8 + ks], acc[t][1], 0, 0, 0);
          }
        }
        cb = nb;
      }
      // ---- epilogue: h1 = relu(acc) -> wave-private h1c rows (bias already in acc) ----
#pragma unroll
      for (int ct = 0; ct < 2; ct++) {
#pragma unroll
        for (int t = 0; t < 2; t++) {
          union { u16 u[4]; uint2 v; } pk;
          pk.u[0] = f2bf(fmaxf(acc[t][ct][0], 0.f));
          pk.u[1] = f2bf(fmaxf(acc[t][ct][1], 0.f));
          pk.u[2] = f2bf(fmaxf(acc[t][ct][2], 0.f));
          pk.u[3] = f2bf(fmaxf(acc[t][ct][3], 0.f));
          *(uint2*)&h1c[(wave * 32 + t * 16 + lnm) * H1STR + ct * 16 + lnq * 4] = pk.v;
        }
      }
      // ---- GEMM2 partial over this 32-wcol window (wave-private, no barrier) ----
      {
#pragma unroll
        for (int t = 0; t < 2; t++) {
          bf16x8 a2 = *(const bf16x8*)&h1c[(wave * 32 + t * 16 + lnm) * H1STR + lnq * 8];
          oacc[t] = __builtin_amdgcn_mfma_f32_16x16x32_bf16(a2, bw, oacc[t], 0, 0, 0);
        }
      }
    }
    // ---- end of source: sigmoid + alpha-weighted accumulate ----
    {
#pragma unroll
      for (int t = 0; t < 2; t++) {
#pragma unroll
        for (int g = 0; g < 4; g++) {
          float sig = 1.f / (1.f + __expf(-(oacc[t][g] + b2v[j])));
          fin[t][g] += alphS[j][wave * 32 + t * 16 + lnq * 4 + g] * sig;
        }
      }
    }
  }
  // combine partials across the 2 source-groups
  if (lnm < NT) {
#pragma unroll
    for (int t = 0; t < 2; t++) {
#pragma unroll
      for (int g = 0; g < 4; g++) {
        int rg = row0 + wave * 32 + t * 16 + lnq * 4 + g;
        atomicAdd(&out[(size_t)rg * NT + lnm], fin[t][g]);
      }
    }
  }
}

extern "C" void kernel_launch(void* const* d_in, const int* in_sizes, int n_in,
                              void* d_out, int out_size, void* d_ws, size_t ws_size,
                              hipStream_t stream) {
  const float* enc = (const float*)d_in[0];
  const float* mu  = (const float*)d_in[1];
  const float* Us  = (const float*)d_in[2];
  const float* W1  = (const float*)d_in[3];
  const float* b1  = (const float*)d_in[4];
  const float* W2  = (const float*)d_in[5];
  const float* b2  = (const float*)d_in[6];
  float* out = (float*)d_out;
  char* ws = (char*)d_ws;
  u16* W1T    = (u16*)(ws + WS_W1T);
  u16* UcatT  = (u16*)(ws + WS_UCT);
  u16* W2T    = (u16*)(ws + WS_W2T);
  float* cvec = (float*)(ws + WS_CVEC);
  float* alphT = (float*)(ws + WS_ALPH);

  prep<<<2560, dim3(32, 8, 1), 0, stream>>>(W1, W1T, Us, UcatT, W2, W2T, mu, cvec);
  routing<<<512, 256, 0, stream>>>(enc, UcatT, cvec, alphT);
  hipMemsetAsync(out, 0, (size_t)out_size * sizeof(float), stream);
  moe_main<<<512, 256, 0, stream>>>(enc, W1T, W2T, alphT, b1, b2, out);
}

// Round 12
// 268.253 us; speedup vs baseline: 1.2064x; 1.0068x over previous
//
#include <hip/hip_runtime.h>
#include <hip/hip_bf16.h>

typedef unsigned short u16;
typedef __bf16 bf16x8 __attribute__((ext_vector_type(8)));
typedef float f32x4 __attribute__((ext_vector_type(4)));

#define NROWS 32768
#define H 512
#define NS 8
#define NR 64
#define NT 12

// workspace layout (bytes)
#define WS_W1T   0            // [8][512 n][512 k] bf16 = 4194304
#define WS_UCT   4194304      // [512 r][512 k] bf16    = 524288
#define WS_W2T   4718592      // [8][16 t][512 k] bf16  = 131072
#define WS_CVEC  4849664      // [8][64] f32            = 2048
#define WS_DIST  4851712      // [8][32768] f32 distances = 1048576

union BFU { __bf16 h; u16 u; };
__device__ __forceinline__ u16 f2bf(float v) { BFU b; b.h = (__bf16)v; return b.u; }

__device__ __forceinline__ void gload16(const u16* g, u16* l) {
  __builtin_amdgcn_global_load_lds(
      (const __attribute__((address_space(1))) unsigned int*)g,
      (__attribute__((address_space(3))) unsigned int*)l, 16, 0, 0);
}

// ---------- fused prep: 3 transposes + compute_c in one launch ----------
__global__ __launch_bounds__(256) void prep(
    const float* __restrict__ W1, u16* __restrict__ W1T,
    const float* __restrict__ Us, u16* __restrict__ UcatT,
    const float* __restrict__ W2, u16* __restrict__ W2T,
    const float* __restrict__ mu, float* __restrict__ cvec) {
  __shared__ float tile[32][33];
  const int bid = blockIdx.x;
  const int tx = threadIdx.x, ty = threadIdx.y;
  if (bid < 2432) {
    const float* in; u16* out; int Rr, Cc, Cpad, b, r0, c0;
    if (bid < 2048) {
      in = W1; out = W1T; Rr = 512; Cc = 512; Cpad = 512;
      r0 = (bid & 15) * 32; c0 = ((bid >> 4) & 15) * 32; b = bid >> 8;
    } else if (bid < 2304) {
      int t2 = bid - 2048; in = Us; out = UcatT; Rr = 512; Cc = 64; Cpad = 64;
      r0 = (t2 & 15) * 32; c0 = ((t2 >> 4) & 1) * 32; b = t2 >> 5;
    } else {
      int t2 = bid - 2304; in = W2; out = W2T; Rr = 512; Cc = 12; Cpad = 16;
      r0 = (t2 & 15) * 32; c0 = 0; b = t2 >> 4;
    }
#pragma unroll
    for (int i = 0; i < 4; i++) {
      int r = r0 + ty + i * 8, c = c0 + tx;
      float v = 0.f;
      if (r < Rr && c < Cc) v = in[((size_t)b * Rr + r) * Cc + c];
      tile[ty + i * 8][tx] = v;
    }
    __syncthreads();
#pragma unroll
    for (int i = 0; i < 4; i++) {
      int c = c0 + ty + i * 8, r = r0 + tx;
      if (c < Cpad && r < Rr) out[((size_t)b * Cpad + c) * Rr + r] = f2bf(tile[tx][ty + i * 8]);
    }
  } else {
    const int tid = ty * 32 + tx;
    const int idx = (bid - 2432) * 4 + (tid >> 6);   // (s,r) pair, 0..511
    const int s = idx >> 6, r = idx & 63, t = tid & 63;
    float acc = 0.f;
#pragma unroll
    for (int k = t; k < H; k += 64) acc += mu[s * H + k] * Us[((size_t)s * H + k) * NR + r];
#pragma unroll
    for (int m = 32; m; m >>= 1) acc += __shfl_xor(acc, m, 64);
    if (t == 0) cvec[idx] = acc;
  }
}

// ---------- shared staging helper: 32 rows x 256 u16, src row stride 512 ----------
__device__ __forceinline__ void stageW16(const u16* __restrict__ g, u16* l, int tid) {
#pragma unroll
  for (int i = 0; i < 4; i++) {
    int flat = tid + i * 256;          // 0..1023
    int r = flat >> 5, u = flat & 31;
    gload16(g + (size_t)r * 512 + (u ^ (r & 7)) * 8, l + flat * 8);
  }
}

// ---------- routing: moe_main-clone phase machinery, outputs distances ----------
// Grid 512 = 256 row-blocks (128 rows, t=2 reuse) x 2 source-groups (4 src).
// Each block stages only its group's 256 KB Ucat slab: 16 phases of 16 KB
// (32 rcols x 256 K), triple-buffered, counted vmcnt(4), 1 barrier/phase —
// per-phase structure identical to moe_main (16 ds_read_b128 / 32 MFMA).
// Per source (4 phases): dsq[t] accumulated per-lane over its rcols, then
// shfl_xor(16/32) sums the lnq groups -> dist written to global distT.
// Softmax over the 8 sources moved to moe_main's prologue.
// chunk q in [0,16): j=q>>2 (source in group), wc=(q>>1)&1, kh=q&1
__device__ __forceinline__ const u16* rchunk(const u16* U, int rcol0, int q) {
  return U + ((size_t)(rcol0 + (q >> 2) * 64 + ((q >> 1) & 1) * 32)) * 512 + (q & 1) * 256;
}

__global__ __launch_bounds__(256, 2) void routing(
    const float* __restrict__ enc, const u16* __restrict__ UcatT,
    const float* __restrict__ cvec, float* __restrict__ distT) {
  __shared__ __align__(16) u16 Wst[3][32 * 256];   // 49152 B
  __shared__ float cvS[256];                       // 1024 B (total 50176)

  const int tid = threadIdx.x;
  const int wave = tid >> 6, lane = tid & 63;
  const int lnm = lane & 15, lnq = lane >> 4;
  const int rb = blockIdx.x >> 1, sg = blockIdx.x & 1;
  const int row0 = rb * 128, sbase = sg * 4;
  const int rcol0 = sbase * 64;   // this group's 256 rcols

  cvS[tid] = cvec[rcol0 + tid];

  // stationary B-operand: RAW enc (no relu), 2 tiles x 16 k-steps = 128 VGPR
  bf16x8 efrag[2][16];
#pragma unroll
  for (int t = 0; t < 2; t++) {
    const float* rp = enc + (size_t)(row0 + wave * 32 + t * 16 + lnm) * H + lnq * 8;
#pragma unroll
    for (int ks = 0; ks < 16; ks++) {
      float4 x0 = *(const float4*)(rp + ks * 32);
      float4 x1 = *(const float4*)(rp + ks * 32 + 4);
      bf16x8 a;
      a[0] = (__bf16)x0.x; a[1] = (__bf16)x0.y; a[2] = (__bf16)x0.z; a[3] = (__bf16)x0.w;
      a[4] = (__bf16)x1.x; a[5] = (__bf16)x1.y; a[6] = (__bf16)x1.z; a[7] = (__bf16)x1.w;
      efrag[t][ks] = a;
    }
  }

  __syncthreads();   // cvS visible; VMEM FIFO drained before raw-barrier loop

  stageW16(rchunk(UcatT, rcol0, 0), Wst[0], tid);
  int cb = 0;
  f32x4 acc[2][2];
#pragma unroll 1
  for (int j = 0; j < 4; j++) {
    float dsq[2] = {0.f, 0.f};
#pragma unroll 1
    for (int wc = 0; wc < 2; wc++) {
#pragma unroll
      for (int t = 0; t < 2; t++) { acc[t][0] = (f32x4){0,0,0,0}; acc[t][1] = (f32x4){0,0,0,0}; }
#pragma unroll
      for (int kh = 0; kh < 2; kh++) {
        const int q = j * 4 + wc * 2 + kh;
        const int nb = (cb == 2) ? 0 : cb + 1;
        if (q + 1 < 16) {
          stageW16(rchunk(UcatT, rcol0, q + 1), Wst[nb], tid);
          asm volatile("s_waitcnt vmcnt(4)" ::: "memory");  // own stage(q) retired
        } else {
          asm volatile("s_waitcnt vmcnt(0)" ::: "memory");
        }
        __builtin_amdgcn_s_barrier();
        const u16* buf = Wst[cb];
#pragma unroll
        for (int ks = 0; ks < 8; ks++) {
          const int uu = ((ks * 4 + lnq) ^ (lnm & 7)) * 8;
          bf16x8 w0 = *(const bf16x8*)&buf[lnm * 256 + uu];
          bf16x8 w1 = *(const bf16x8*)&buf[(16 + lnm) * 256 + uu];
#pragma unroll
          for (int t = 0; t < 2; t++) {
            acc[t][0] = __builtin_amdgcn_mfma_f32_16x16x32_bf16(w0, efrag[t][kh * 8 + ks], acc[t][0], 0, 0, 0);
            acc[t][1] = __builtin_amdgcn_mfma_f32_16x16x32_bf16(w1, efrag[t][kh * 8 + ks], acc[t][1], 0, 0, 0);
          }
        }
        cb = nb;
      }
      // dsq accumulate: lane holds proj for encrow (t*16+lnm), rcols ct*16+lnq*4+g
#pragma unroll
      for (int ct = 0; ct < 2; ct++) {
        float4 cv4 = *(const float4*)&cvS[j * 64 + wc * 32 + ct * 16 + lnq * 4];
#pragma unroll
        for (int t = 0; t < 2; t++) {
          float d0 = acc[t][ct][0] - cv4.x, d1 = acc[t][ct][1] - cv4.y;
          float d2 = acc[t][ct][2] - cv4.z, d3 = acc[t][ct][3] - cv4.w;
          dsq[t] += d0 * d0 + d1 * d1 + d2 * d2 + d3 * d3;
        }
      }
    }
    // sum over the 4 lnq groups (lane bits 4,5)
#pragma unroll
    for (int t = 0; t < 2; t++) {
      dsq[t] += __shfl_xor(dsq[t], 16, 64);
      dsq[t] += __shfl_xor(dsq[t], 32, 64);
    }
    if (lnq == 0) {
#pragma unroll
      for (int t = 0; t < 2; t++)
        distT[(size_t)(sbase + j) * NROWS + row0 + wave * 32 + t * 16 + lnm] = sqrtf(dsq[t]);
    }
  }
}

// ---------- main classifier (r11 structure; softmax prologue added) ----------
// Grid: 512 blocks = 256 row-blocks (128 rows) x 2 source-groups (4 sources).
// Triple-buffered 16 KB chunks, counted-vmcnt single barrier per half-chunk,
// hoisted epilogue operands, bias-folded acc init, no setprio.
#define H1STR 40   // u16 row stride (80 B)

// chunk index q in [0,128): j=q>>5 (source), wc=(q>>1)&15, kh=q&1
__device__ __forceinline__ const u16* chunk_base(const u16* W1g, int q) {
  return W1g + ((size_t)(q >> 5) * 512 + ((q >> 1) & 15) * 32) * 512 + (q & 1) * 256;
}

__global__ __launch_bounds__(256, 2) void moe_main(
    const float* __restrict__ enc, const u16* __restrict__ W1T,
    const u16* __restrict__ W2T, const float* __restrict__ distT,
    const float* __restrict__ b1g, const float* __restrict__ b2g,
    float* __restrict__ out) {
  __shared__ __align__(16) u16 Wst[3][32 * 256];   // 49152 B (triple buffer)
  __shared__ __align__(16) u16 h1c[128 * H1STR];   // 10240 B
  __shared__ float alphS[4][128];                  // 2048 B  (total 61440 B)

  const int tid = threadIdx.x;
  const int wave = tid >> 6, lane = tid & 63;
  const int lnm = lane & 15, lnq = lane >> 4;
  const int rb = blockIdx.x >> 1, sg = blockIdx.x & 1;
  const int row0 = rb * 128, sbase = sg * 4;

  // softmax over 8 source distances (was routing's tail)
  if (tid < 128) {
    float dv[NS], e[NS];
#pragma unroll
    for (int s2 = 0; s2 < NS; s2++) dv[s2] = distT[(size_t)s2 * NROWS + row0 + tid];
    float dmin = dv[0];
#pragma unroll
    for (int s2 = 1; s2 < NS; s2++) dmin = fminf(dmin, dv[s2]);
    float den = 0.f;
#pragma unroll
    for (int s2 = 0; s2 < NS; s2++) { e[s2] = __expf(dmin - dv[s2]); den += e[s2]; }
    float inv = 1.f / den;
#pragma unroll
    for (int jj = 0; jj < 4; jj++) alphS[jj][tid] = e[sbase + jj] * inv;
  }

  float b2v[4];
#pragma unroll
  for (int j = 0; j < 4; j++) b2v[j] = (lnm < NT) ? b2g[(sbase + j) * NT + lnm] : 0.f;

  // stationary B-operand: h0 = relu(enc) bf16, 2 tiles x 16 k-steps = 128 VGPR
  bf16x8 efrag[2][16];
#pragma unroll
  for (int t = 0; t < 2; t++) {
    const float* rp = enc + (size_t)(row0 + wave * 32 + t * 16 + lnm) * H + lnq * 8;
#pragma unroll
    for (int ks = 0; ks < 16; ks++) {
      float4 x0 = *(const float4*)(rp + ks * 32);
      float4 x1 = *(const float4*)(rp + ks * 32 + 4);
      bf16x8 a;
      a[0] = (__bf16)fmaxf(x0.x, 0.f); a[1] = (__bf16)fmaxf(x0.y, 0.f);
      a[2] = (__bf16)fmaxf(x0.z, 0.f); a[3] = (__bf16)fmaxf(x0.w, 0.f);
      a[4] = (__bf16)fmaxf(x1.x, 0.f); a[5] = (__bf16)fmaxf(x1.y, 0.f);
      a[6] = (__bf16)fmaxf(x1.z, 0.f); a[7] = (__bf16)fmaxf(x1.w, 0.f);
      efrag[t][ks] = a;
    }
  }

  // make alphS writes visible before switching to raw s_barrier sync
  __syncthreads();

  const u16* W1g = W1T + (size_t)sbase * 512 * 512;
  stageW16(chunk_base(W1g, 0), Wst[0], tid);
  int cb = 0;
  f32x4 acc[2][2];
  float fin[2][4] = {};
#pragma unroll 1
  for (int j = 0; j < 4; j++) {
    const int s = sbase + j;
    f32x4 oacc[2] = {};
#pragma unroll 1
    for (int wc = 0; wc < 16; wc++) {
      const int q = j * 32 + wc * 2;
      // hoisted epilogue operands — issued BEFORE this wc's stages
      float4 bq0 = *(const float4*)&b1g[s * H + wc * 32 + lnq * 4];
      float4 bq1 = *(const float4*)&b1g[s * H + wc * 32 + 16 + lnq * 4];
      bf16x8 bw = *(const bf16x8*)&W2T[((size_t)s * 16 + lnm) * H + wc * 32 + lnq * 8];
      asm volatile("" ::: "memory");   // pin issue order: loads stay at wc-top
      // ======== kh = 0 : compute chunk q from Wst[cb] ========
      {
        const int nb = (cb == 2) ? 0 : cb + 1;
        stageW16(chunk_base(W1g, q + 1), Wst[nb], tid);   // q+1 <= 127 always
        asm volatile("s_waitcnt vmcnt(7)" ::: "memory");  // retires stage(q); keeps epi + stage(q+1)
        __builtin_amdgcn_s_barrier();
        const u16* buf = Wst[cb];
        // bias-folded accumulator init
#pragma unroll
        for (int t = 0; t < 2; t++) {
          acc[t][0] = (f32x4){bq0.x, bq0.y, bq0.z, bq0.w};
          acc[t][1] = (f32x4){bq1.x, bq1.y, bq1.z, bq1.w};
        }
#pragma unroll
        for (int ks = 0; ks < 8; ks++) {
          const int uu = ((ks * 4 + lnq) ^ (lnm & 7)) * 8;
          bf16x8 w0 = *(const bf16x8*)&buf[lnm * 256 + uu];
          bf16x8 w1 = *(const bf16x8*)&buf[(16 + lnm) * 256 + uu];
#pragma unroll
          for (int t = 0; t < 2; t++) {
            acc[t][0] = __builtin_amdgcn_mfma_f32_16x16x32_bf16(w0, efrag[t][ks], acc[t][0], 0, 0, 0);
            acc[t][1] = __builtin_amdgcn_mfma_f32_16x16x32_bf16(w1, efrag[t][ks], acc[t][1], 0, 0, 0);
          }
        }
        cb = nb;
      }
      // ======== kh = 1 : compute chunk q+1 from Wst[cb] ========
      {
        const int nb = (cb == 2) ? 0 : cb + 1;
        if (q + 2 < 128) {
          stageW16(chunk_base(W1g, q + 2), Wst[nb], tid);
          asm volatile("s_waitcnt vmcnt(4)" ::: "memory");  // retires epi + stage(q+1)
        } else {
          asm volatile("s_waitcnt vmcnt(0)" ::: "memory");  // last chunk: drain
        }
        __builtin_amdgcn_s_barrier();
        const u16* buf = Wst[cb];
#pragma unroll
        for (int ks = 0; ks < 8; ks++) {
          const int uu = ((ks * 4 + lnq) ^ (lnm & 7)) * 8;
          bf16x8 w0 = *(const bf16x8*)&buf[lnm * 256 + uu];
          bf16x8 w1 = *(const bf16x8*)&buf[(16 + lnm) * 256 + uu];
#pragma unroll
          for (int t = 0; t < 2; t++) {
            acc[t][0] = __builtin_amdgcn_mfma_f32_16x16x32_bf16(w0, efrag[t][8 + ks], acc[t][0], 0, 0, 0);
            acc[t][1] = __builtin_amdgcn_mfma_f32_16x16x32_bf16(w1, efrag[t][8 + ks], acc[t][1], 0, 0, 0);
          }
        }
        cb = nb;
      }
      // ---- epilogue: h1 = relu(acc) -> wave-private h1c rows (bias already in acc) ----
#pragma unroll
      for (int ct = 0; ct < 2; ct++) {
#pragma unroll
        for (int t = 0; t < 2; t++) {
          union { u16 u[4]; uint2 v; } pk;
          pk.u[0] = f2bf(fmaxf(acc[t][ct][0], 0.f));
          pk.u[1] = f2bf(fmaxf(acc[t][ct][1], 0.f));
          pk.u[2] = f2bf(fmaxf(acc[t][ct][2], 0.f));
          pk.u[3] = f2bf(fmaxf(acc[t][ct][3], 0.f));
          *(uint2*)&h1c[(wave * 32 + t * 16 + lnm) * H1STR + ct * 16 + lnq * 4] = pk.v;
        }
      }
      // ---- GEMM2 partial over this 32-wcol window (wave-private, no barrier) ----
      {
#pragma unroll
        for (int t = 0; t < 2; t++) {
          bf16x8 a2 = *(const bf16x8*)&h1c[(wave * 32 + t * 16 + lnm) * H1STR + lnq * 8];
          oacc[t] = __builtin_amdgcn_mfma_f32_16x16x32_bf16(a2, bw, oacc[t], 0, 0, 0);
        }
      }
    }
    // ---- end of source: sigmoid + alpha-weighted accumulate ----
    {
#pragma unroll
      for (int t = 0; t < 2; t++) {
#pragma unroll
        for (int g = 0; g < 4; g++) {
          float sig = 1.f / (1.f + __expf(-(oacc[t][g] + b2v[j])));
          fin[t][g] += alphS[j][wave * 32 + t * 16 + lnq * 4 + g] * sig;
        }
      }
    }
  }
  // combine partials across the 2 source-groups
  if (lnm < NT) {
#pragma unroll
    for (int t = 0; t < 2; t++) {
#pragma unroll
      for (int g = 0; g < 4; g++) {
        int rg = row0 + wave * 32 + t * 16 + lnq * 4 + g;
        atomicAdd(&out[(size_t)rg * NT + lnm], fin[t][g]);
      }
    }
  }
}

extern "C" void kernel_launch(void* const* d_in, const int* in_sizes, int n_in,
                              void* d_out, int out_size, void* d_ws, size_t ws_size,
                              hipStream_t stream) {
  const float* enc = (const float*)d_in[0];
  const float* mu  = (const float*)d_in[1];
  const float* Us  = (const float*)d_in[2];
  const float* W1  = (const float*)d_in[3];
  const float* b1  = (const float*)d_in[4];
  const float* W2  = (const float*)d_in[5];
  const float* b2  = (const float*)d_in[6];
  float* out = (float*)d_out;
  char* ws = (char*)d_ws;
  u16* W1T    = (u16*)(ws + WS_W1T);
  u16* UcatT  = (u16*)(ws + WS_UCT);
  u16* W2T    = (u16*)(ws + WS_W2T);
  float* cvec = (float*)(ws + WS_CVEC);
  float* distT = (float*)(ws + WS_DIST);

  prep<<<2560, dim3(32, 8, 1), 0, stream>>>(W1, W1T, Us, UcatT, W2, W2T, mu, cvec);
  routing<<<512, 256, 0, stream>>>(enc, UcatT, cvec, distT);
  hipMemsetAsync(out, 0, (size_t)out_size * sizeof(float), stream);
  moe_main<<<512, 256, 0, stream>>>(enc, W1T, W2T, distT, b1, b2, out);
}